// Round 18
// baseline (137.860 us; speedup 1.0000x reference)
//
#include <hip/hip_runtime.h>

// ---------------------------------------------------------------------------
// MultiHeadAttention forward, MI355X (gfx950).
// fp32->bf16 convert; Q/K/V projections (bf16 MFMA GEMM, BK=32, XCD-chunked
// block mapping); flash attention v8c (32x32x16 MFMA split-KV x2, 8 waves,
// K dbuf + V single-buffer (issue-early/write-late, 2nd barrier), LDS 51.5KB
// for 2 blocks/CU, XCD-chunked grid, in-register P, defer-max); out proj.
// ---------------------------------------------------------------------------

#define D_MODEL 1024
#define NHEADS  16
#define DKH     64
#define SEQ     2048
#define BATCH   2
#define MTOT    (BATCH * SEQ)            // 4096 rows
#define XE      ((long)MTOT * D_MODEL)   // 4194304 elems
#define WE      ((long)D_MODEL * D_MODEL)
#define QSCALE  0.18033688011112042f     // 0.125 * log2(e): softmax in exp2 domain

typedef __attribute__((ext_vector_type(8)))  short short8v;   // 8 x bf16
typedef __attribute__((ext_vector_type(4)))  short short4v;   // 4 x bf16
typedef __attribute__((ext_vector_type(4)))  float f32x4;     // 16x16 C/D frag
typedef __attribute__((ext_vector_type(16))) float f32x16;    // 32x32 C/D frag

typedef __attribute__((address_space(1))) void as1_void;
typedef __attribute__((address_space(3))) void as3_void;

__device__ __forceinline__ void gload16(const void* g, void* l) {
    __builtin_amdgcn_global_load_lds((const as1_void*)g, (as3_void*)l, 16, 0, 0);
}

__device__ __forceinline__ unsigned short f2bf(float x) {
    unsigned int u = __float_as_uint(x);
    u += 0x7FFFu + ((u >> 16) & 1u);     // RNE
    return (unsigned short)(u >> 16);
}

// native v_exp_f32: computes 2^x (avoid __exp2f: glibc name collision)
__device__ __forceinline__ float fexp2(float x) {
    return __builtin_amdgcn_exp2f(x);
}

// hardware packed f32x2 -> bf16x2 (one VALU op for two converts)
__device__ __forceinline__ unsigned int cvt_pk_bf16(float lo, float hi) {
    unsigned int r;
    asm("v_cvt_pk_bf16_f32 %0, %1, %2" : "=v"(r) : "v"(lo), "v"(hi));
    return r;
}

// XOR swizzle for [rows][64 bf16] LDS tiles (128B rows).
__device__ __forceinline__ int swz_u(int row, int col) {
    int byte = (col << 1) ^ ((row & 7) << 4);
    return (row << 6) + (byte >> 1);
}

// Vt swizzle: slot bits from (d&6)|((d>>3)&1): write pairs and reads stay low-way.
__device__ __forceinline__ int swz_v(int d, int kv) {
    int slot = (d & 6) | ((d >> 3) & 1);
    int byte = (kv << 1) ^ (slot << 4);
    return (d << 6) + (byte >> 1);
}

// ---------------------------------------------------------------------------
// fp32 -> bf16 convert, 7 arrays in one launch (blockIdx.y selects array)
// ---------------------------------------------------------------------------
struct ConvArgs {
    const float*    src[7];
    unsigned short* dst[7];
    int             n4[7];
};

__global__ __launch_bounds__(256) void convert_kernel(ConvArgs a) {
    int z = blockIdx.y;
    const float4*   s = (const float4*)a.src[z];
    unsigned short* d = a.dst[z];
    int n = a.n4[z];
    for (int i = blockIdx.x * blockDim.x + threadIdx.x; i < n;
         i += gridDim.x * blockDim.x) {
        float4 v = s[i];
        ushort4 o;
        o.x = f2bf(v.x); o.y = f2bf(v.y); o.z = f2bf(v.z); o.w = f2bf(v.w);
        *(ushort4*)(d + 4L * i) = o;
    }
}

// ---------------------------------------------------------------------------
// GEMM: C[M,N] = A[M,K] * Bm[N,K]^T  (both K-major), + bias, * scale.
// 128x128 tile, BK=32, 4 waves (2x2), 16x16x32 bf16 MFMA, global_load_lds.
// m0/n0 passed in (callers apply XCD-chunked block mapping).
// ---------------------------------------------------------------------------
__device__ __forceinline__ void stv(float* p, float v)          { *p = v; }
__device__ __forceinline__ void stv(unsigned short* p, float v) { *p = f2bf(v); }

template <typename OutT>
__device__ __forceinline__ void gemm_core(const unsigned short* __restrict__ A,
                                          const unsigned short* __restrict__ Bm,
                                          const float* __restrict__ bias,
                                          OutT* __restrict__ C,
                                          int K, int N, float scale,
                                          long m0, long n0) {
    __shared__ unsigned short As[128 * 32];
    __shared__ unsigned short Bs[128 * 32];

    const int t    = threadIdx.x;
    const int lane = t & 63;
    const int w    = t >> 6;
    const int wm   = w >> 1, wn = w & 1;
    const int l15  = lane & 15, g = lane >> 4;

    f32x4 acc[4][4] = {};

    const int idx0 = t, idx1 = t + 256;
    const int r0 = idx0 >> 2, c0 = (idx0 & 3) * 8;
    const int r1 = idx1 >> 2, c1 = (idx1 & 3) * 8;
    const unsigned short* pa0 = A  + (m0 + r0) * K + c0;
    const unsigned short* pa1 = A  + (m0 + r1) * K + c1;
    const unsigned short* pb0 = Bm + (n0 + r0) * K + c0;
    const unsigned short* pb1 = Bm + (n0 + r1) * K + c1;

    for (int k0 = 0; k0 < K; k0 += 32) {
        gload16(pa0 + k0, &As[idx0 * 8]);
        gload16(pa1 + k0, &As[idx1 * 8]);
        gload16(pb0 + k0, &Bs[idx0 * 8]);
        gload16(pb1 + k0, &Bs[idx1 * 8]);
        __syncthreads();   // drains vmcnt -> LDS valid

        short8v af[4], bf_[4];
#pragma unroll
        for (int mf = 0; mf < 4; ++mf)
            af[mf] = *(const short8v*)&As[(wm * 64 + mf * 16 + l15) * 32 + g * 8];
#pragma unroll
        for (int nf = 0; nf < 4; ++nf)
            bf_[nf] = *(const short8v*)&Bs[(wn * 64 + nf * 16 + l15) * 32 + g * 8];
#pragma unroll
        for (int mf = 0; mf < 4; ++mf)
#pragma unroll
            for (int nf = 0; nf < 4; ++nf)
                acc[mf][nf] = __builtin_amdgcn_mfma_f32_16x16x32_bf16(
                    af[mf], bf_[nf], acc[mf][nf], 0, 0, 0);
        __syncthreads();   // reads done before restage
    }

    float bvv[4];
#pragma unroll
    for (int nf = 0; nf < 4; ++nf)
        bvv[nf] = bias[n0 + wn * 64 + nf * 16 + l15];

#pragma unroll
    for (int mf = 0; mf < 4; ++mf)
#pragma unroll
        for (int nf = 0; nf < 4; ++nf)
#pragma unroll
            for (int r = 0; r < 4; ++r) {
                // m89-verified C/D layout: col = lane&15, row = (lane>>4)*4+reg
                long row = m0 + wm * 64 + mf * 16 + g * 4 + r;
                long col = n0 + wn * 64 + nf * 16 + l15;
                float v = (acc[mf][nf][r] + bvv[nf]) * scale;
                stv(C + row * (long)N + col, v);
            }
}

// proj: 768 blocks, 1-D. XCD-chunked decode (T1, bijective: 768 % 8 == 0).
__global__ __launch_bounds__(256) void proj_kernel(
    const unsigned short* __restrict__ xb, const unsigned short* __restrict__ wb,
    const float* __restrict__ bq, const float* __restrict__ bk,
    const float* __restrict__ bv, unsigned short* __restrict__ qkv) {
    const int bid = blockIdx.x;
    const int xcd = bid & 7;
    const int k   = bid >> 3;            // 0..95 = 4(y) x 8(x) x 3(z)
    const int ty  = (xcd << 2) | (k & 3);
    const int tx  = (k >> 2) & 7;
    const int z   = k >> 5;
    const float* bias = (z == 0) ? bq : (z == 1) ? bk : bv;
    float scale = (z == 0) ? QSCALE : 1.0f;
    gemm_core<unsigned short>(xb + (long)z * XE, wb + (long)z * WE, bias,
                              qkv + (long)z * XE, D_MODEL, D_MODEL, scale,
                              (long)ty * 128, (long)tx * 128);
}

// out: 256 blocks, 1-D, same chunked decode (256 % 8 == 0).
__global__ __launch_bounds__(256) void out_kernel(
    const unsigned short* __restrict__ ob, const unsigned short* __restrict__ wo,
    const float* __restrict__ bo, float* __restrict__ out) {
    const int bid = blockIdx.x;
    const int xcd = bid & 7;
    const int k   = bid >> 3;            // 0..31 = 4(y) x 8(x)
    const int ty  = (xcd << 2) | (k & 3);
    const int tx  = k >> 2;
    gemm_core<float>(ob, wo, bo, out, D_MODEL, D_MODEL, 1.0f,
                     (long)ty * 128, (long)tx * 128);
}

// ---------------------------------------------------------------------------
// Flash attention v8c: 512 threads = 8 waves = 4 q-groups x 2 kv-splits,
// 32x32x16 MFMA. LDS trimmed to 51.5 KB (vs v8b's 69 KB that appears to
// have capped residency at 1 block/CU): K double-buffered, V SINGLE-buffered
// with issue-early (regs in flight over compute) / write-late (after a 2nd
// barrier post-PV). XCD-chunked grid: each XCD owns 4 heads x 16 q-blocks.
// ---------------------------------------------------------------------------
#define TSZ 4096   // elems per 64x64 tile slot
#define NTS 16     // super-iters (2048 / 128)

__global__ __launch_bounds__(512) void attn_kernel(
    const unsigned short* __restrict__ Qb, const unsigned short* __restrict__ Kb,
    const unsigned short* __restrict__ Vb, unsigned short* __restrict__ Ob) {
    __shared__ alignas(16) unsigned char SM[52736];
    unsigned short* KsB   = (unsigned short*)SM;            // [2 dbuf][2 tile][TSZ] 32KB
    unsigned short* VtB   = (unsigned short*)(SM + 32768);  // [2 tile][TSZ] 16KB single
    float*          corrS = (float*)(SM + 49152);           // [8 waves][32]
    float*          mS    = (float*)(SM + 50176);           // [2 sp][4 qg][32]
    float*          lS    = (float*)(SM + 51200);           // [2 sp][4 qg][32]
    float*          lTot  = (float*)(SM + 52224);           // [4 qg][32]
    float*          comb  = (float*)SM;                     // 32 KB alias of KsB

    const int t = threadIdx.x, lane = t & 63, w = t >> 6;
    const int l31 = lane & 31, h = lane >> 5;
    const int qg = w & 3, sp = w >> 2;
    // XCD-chunked decode: 512 blocks, xcd owns heads 4*xcd..4*xcd+3
    const int bid = blockIdx.x;
    const int xcd = bid & 7;
    const int kk2 = bid >> 3;              // 0..63
    const int bh  = (xcd << 2) | (kk2 & 3);
    const int qb  = kk2 >> 2;              // 0..15
    const long headoff = (long)(bh >> 4) * SEQ * D_MODEL + (long)(bh & 15) * DKH;
    const int q0w = qb * 128 + qg * 32;

    // Q rows -> B-frag registers: N-col = q = l31, k-elems d = step*16+h*8+j
    short8v qf[4];
#pragma unroll
    for (int step = 0; step < 4; ++step)
        qf[step] = *(const short8v*)(Qb + headoff +
            (long)(q0w + l31) * D_MODEL + step * 16 + h * 8);

    f32x16 o[2] = {};        // O cols d = db*32+l31; rows q = (r&3)+8(r>>2)+4h
    float mrun = -3.0e38f;   // running max, q = l31 domain
    float lrun = 0.f;        // running denom, q = l31 domain

    // V staging: 512 threads cover 2 tiles; t<256 -> tile 0, else tile 1
    const int vtile = t >> 8, t8 = t & 255;
    const int vd0  = (t8 & 31) * 2;
    const int vkv0 = (t8 >> 5) * 8;
    // K staging: one gload16 per tile per thread
    const int kr0 = t >> 3, ks0 = t & 7;

    unsigned int va[8];   // in-flight V gather regs (issue-early / write-late)

#define ISSUE_V(kt)                                                        \
    _Pragma("unroll")                                                      \
    for (int j = 0; j < 8; ++j)                                            \
        va[j] = *(const unsigned int*)(Vb + headoff +                      \
            (long)((kt) + vtile * 64 + vkv0 + j) * D_MODEL + vd0);

#define ISSUE_K(kt, dbuf)                                                  \
    gload16(Kb + headoff + (long)((kt) + kr0) * D_MODEL +                  \
                ((ks0 ^ (kr0 & 7)) << 3),                                  \
            &KsB[((dbuf) * 2 + 0) * TSZ + t * 8]);                         \
    gload16(Kb + headoff + (long)((kt) + 64 + kr0) * D_MODEL +             \
                ((ks0 ^ (kr0 & 7)) << 3),                                  \
            &KsB[((dbuf) * 2 + 1) * TSZ + t * 8]);

#define WRITE_V()                                                          \
    {                                                                      \
        short8v ra, rb;                                                    \
        _Pragma("unroll")                                                  \
        for (int j = 0; j < 8; ++j) {                                      \
            ra[j] = (short)(va[j] & 0xffffu);                              \
            rb[j] = (short)(va[j] >> 16);                                  \
        }                                                                  \
        unsigned short* vt = &VtB[vtile * TSZ];                            \
        *(short8v*)&vt[swz_v(vd0,     vkv0)] = ra;                         \
        *(short8v*)&vt[swz_v(vd0 + 1, vkv0)] = rb;                         \
    }

    // ---- prologue: drain Q loads, stage chunk 0 (K->dbuf0, V->LDS) ----
    asm volatile("s_waitcnt vmcnt(0)" ::: "memory");
    ISSUE_V(0);
    ISSUE_K(0, 0);
    WRITE_V();               // compiler waits va; K stays in flight
    int cur = 0;

    for (int it = 0; it < NTS; ++it) {
        const int nxt = cur ^ 1;
        const int ktn = ((it + 1) & (NTS - 1)) * 128;   // wrapped prefetch
        ISSUE_V(ktn);        // V(next) -> regs, in flight across this compute
        ISSUE_K(ktn, nxt);
        // outstanding: K(cur)=2 + V(nxt)=8 + K(nxt)=2 = 12; complete oldest 2
        asm volatile("s_waitcnt vmcnt(10)" ::: "memory");
        asm volatile("s_waitcnt lgkmcnt(0)" ::: "memory");
        __builtin_amdgcn_sched_barrier(0);
        __builtin_amdgcn_s_barrier();
        __builtin_amdgcn_sched_barrier(0);

        const int kO = (cur * 2 + sp) * TSZ;   // this wave's K tile slot
        const int vO = sp * TSZ;               // this wave's V tile slot

        // ---- S^T = K * Q^T : st[b] covers kv-block b (32 kv x 32 q) ----
        f32x16 st[2] = {};
        __builtin_amdgcn_s_setprio(1);
#pragma unroll
        for (int step = 0; step < 4; ++step) {
            short8v kf0 = *(const short8v*)&KsB[kO + swz_u(l31,      step * 16 + h * 8)];
            st[0] = __builtin_amdgcn_mfma_f32_32x32x16_bf16(kf0, qf[step], st[0], 0, 0, 0);
            short8v kf1 = *(const short8v*)&KsB[kO + swz_u(32 + l31, step * 16 + h * 8)];
            st[1] = __builtin_amdgcn_mfma_f32_32x32x16_bf16(kf1, qf[step], st[1], 0, 0, 0);
        }
        __builtin_amdgcn_s_setprio(0);

        // ---- softmax: max3-tree reduce, defer-max THR=8, exp2 domain ----
        float m01[8];
#pragma unroll
        for (int j = 0; j < 8; ++j)
            m01[j] = fmaxf(fmaxf(st[0][2 * j], st[0][2 * j + 1]),
                           fmaxf(st[1][2 * j], st[1][2 * j + 1]));
        float vmax = fmaxf(fmaxf(fmaxf(fmaxf(m01[0], m01[1]), m01[2]),
                                 fmaxf(fmaxf(m01[3], m01[4]), m01[5])),
                           fmaxf(m01[6], m01[7]));
        vmax = fmaxf(vmax, __shfl_xor(vmax, 32));

        const bool grow = __any(vmax > mrun + 8.0f);
        if (grow) {
            float mnew = fmaxf(mrun, vmax);
            float corr = fexp2(mrun - mnew);
            mrun = mnew;
            lrun *= corr;                       // scalar, q = l31 domain
            if (lane < 32) corrS[w * 32 + l31] = corr;
#pragma unroll
            for (int q2 = 0; q2 < 4; ++q2) {
                float4 cv = *(const float4*)&corrS[w * 32 + q2 * 8 + h * 4];
#pragma unroll
                for (int r3 = 0; r3 < 4; ++r3) {
                    o[0][q2 * 4 + r3] *= cv[r3];
                    o[1][q2 * 4 + r3] *= cv[r3];
                }
            }
        }

        float ps = 0.f;
#pragma unroll
        for (int b = 0; b < 2; ++b)
#pragma unroll
            for (int r = 0; r < 16; ++r) {
                st[b][r] = fexp2(st[b][r] - mrun);
                ps += st[b][r];
            }
        ps += __shfl_xor(ps, 32);               // both kv-halves -> full sum
        lrun += ps;

        // ---- PV: in-register P (cvt_pk + permlane32_swap), no LDS ----
        __builtin_amdgcn_s_setprio(1);
#pragma unroll
        for (int b = 0; b < 2; ++b)
#pragma unroll
            for (int s = 0; s < 2; ++s) {
                unsigned int u  = cvt_pk_bf16(st[b][s * 8 + 0], st[b][s * 8 + 1]);
                unsigned int u2 = cvt_pk_bf16(st[b][s * 8 + 2], st[b][s * 8 + 3]);
                unsigned int v  = cvt_pk_bf16(st[b][s * 8 + 4], st[b][s * 8 + 5]);
                unsigned int v2 = cvt_pk_bf16(st[b][s * 8 + 6], st[b][s * 8 + 7]);
                asm("v_permlane32_swap_b32 %0, %1" : "+v"(u),  "+v"(v));
                asm("v_permlane32_swap_b32 %0, %1" : "+v"(u2), "+v"(v2));
                uint4 pu = {u, u2, v, v2};
                short8v pa = __builtin_bit_cast(short8v, pu);
                short8v vb0 = *(const short8v*)&VtB[vO + swz_v(l31,      b * 32 + s * 16 + h * 8)];
                o[0] = __builtin_amdgcn_mfma_f32_32x32x16_bf16(pa, vb0, o[0], 0, 0, 0);
                short8v vb1 = *(const short8v*)&VtB[vO + swz_v(32 + l31, b * 32 + s * 16 + h * 8)];
                o[1] = __builtin_amdgcn_mfma_f32_32x32x16_bf16(pa, vb1, o[1], 0, 0, 0);
            }
        __builtin_amdgcn_s_setprio(0);

        // ---- barrier2: all PV V-reads done -> safe to overwrite V LDS ----
        __builtin_amdgcn_sched_barrier(0);
        __builtin_amdgcn_s_barrier();
        __builtin_amdgcn_sched_barrier(0);
        WRITE_V();            // next tile's V from va regs (landed during compute)
        cur = nxt;
    }

    // ---- drain stray K/V gloads before aliasing SM with combine area ----
    asm volatile("s_waitcnt vmcnt(0)" ::: "memory");

    // ---- split-KV pair combine: (qg, sp=0) += (qg, sp=1) ----
    if (lane < 32) {
        mS[(sp * 4 + qg) * 32 + l31] = mrun;
        lS[(sp * 4 + qg) * 32 + l31] = lrun;
    }
    __syncthreads();   // all K reads done; mS/lS visible

    // rescale own o to the pair max (per o-row q = q2*8 + h*4 + r3)
#pragma unroll
    for (int q2 = 0; q2 < 4; ++q2) {
        float4 ma = *(const float4*)&mS[(0 * 4 + qg) * 32 + q2 * 8 + h * 4];
        float4 mb = *(const float4*)&mS[(1 * 4 + qg) * 32 + q2 * 8 + h * 4];
#pragma unroll
        for (int r3 = 0; r3 < 4; ++r3) {
            float mt = fmaxf(ma[r3], mb[r3]);
            float mo = (sp == 0) ? ma[r3] : mb[r3];
            float sc = fexp2(mo - mt);
            o[0][q2 * 4 + r3] *= sc;
            o[1][q2 * 4 + r3] *= sc;
        }
    }

    // sp=1 ships 32 floats/lane; layout [c:32][qg:4][lane:64] (aliases Ks)
    if (sp == 1) {
#pragma unroll
        for (int c = 0; c < 16; ++c) {
            comb[(c)        * 256 + qg * 64 + lane] = o[0][c];
            comb[(c + 16)   * 256 + qg * 64 + lane] = o[1][c];
        }
    }
    __syncthreads();
    if (sp == 0) {
#pragma unroll
        for (int c = 0; c < 16; ++c) {
            o[0][c] += comb[(c)      * 256 + qg * 64 + lane];
            o[1][c] += comb[(c + 16) * 256 + qg * 64 + lane];
        }
        // combined denom in q = l31 domain, redistribute via lTot
        float m0 = mS[(0 * 4 + qg) * 32 + l31];
        float m1 = mS[(1 * 4 + qg) * 32 + l31];
        float mt = fmaxf(m0, m1);
        float lt = lS[(0 * 4 + qg) * 32 + l31] * fexp2(m0 - mt) +
                   lS[(1 * 4 + qg) * 32 + l31] * fexp2(m1 - mt);
        if (lane < 32) lTot[qg * 32 + l31] = lt;
        // in-wave DS ordering: our own lTot writes are visible to our reads
        // ---- epilogue: O /= l ----
#pragma unroll
        for (int q2 = 0; q2 < 4; ++q2)
#pragma unroll
            for (int r3 = 0; r3 < 4; ++r3) {
                float inv = 1.f / (lTot[qg * 32 + q2 * 8 + h * 4 + r3] + 1e-9f);
                long rowoff = headoff +
                    (long)(q0w + q2 * 8 + h * 4 + r3) * D_MODEL;
                Ob[rowoff + l31]      = f2bf(o[0][q2 * 4 + r3] * inv);
                Ob[rowoff + 32 + l31] = f2bf(o[1][q2 * 4 + r3] * inv);
            }
    }
#undef ISSUE_V
#undef ISSUE_K
#undef WRITE_V
}

// ---------------------------------------------------------------------------
// Launch
// ---------------------------------------------------------------------------
extern "C" void kernel_launch(void* const* d_in, const int* in_sizes, int n_in,
                              void* d_out, int out_size, void* d_ws, size_t ws_size,
                              hipStream_t stream) {
    // d_in order: 0 q, 1 k, 2 v, 3 Wq, 4 bq, 5 Wk, 6 bk, 7 Wv, 8 bv, 9 Wo, 10 bo
    unsigned short* ws  = (unsigned short*)d_ws;
    unsigned short* xb  = ws;                       // 3*XE  bf16 inputs q,k,v
    unsigned short* wb  = ws + 3L * XE;             // 4*WE  bf16 weights
    unsigned short* qkv = ws + 3L * XE + 4L * WE;   // 3*XE  Q(scaled), K, V
    unsigned short* ob  = qkv + 3L * XE;            // XE    attention output

    ConvArgs ca;
    ca.src[0] = (const float*)d_in[0]; ca.dst[0] = xb;           ca.n4[0] = (int)(XE / 4);
    ca.src[1] = (const float*)d_in[1]; ca.dst[1] = xb + XE;      ca.n4[1] = (int)(XE / 4);
    ca.src[2] = (const float*)d_in[2]; ca.dst[2] = xb + 2L * XE; ca.n4[2] = (int)(XE / 4);
    ca.src[3] = (const float*)d_in[3]; ca.dst[3] = wb;           ca.n4[3] = (int)(WE / 4);
    ca.src[4] = (const float*)d_in[5]; ca.dst[4] = wb + WE;      ca.n4[4] = (int)(WE / 4);
    ca.src[5] = (const float*)d_in[7]; ca.dst[5] = wb + 2L * WE; ca.n4[5] = (int)(WE / 4);
    ca.src[6] = (const float*)d_in[9]; ca.dst[6] = wb + 3L * WE; ca.n4[6] = (int)(WE / 4);

    hipLaunchKernelGGL(convert_kernel, dim3(512, 7), dim3(256), 0, stream, ca);

    hipLaunchKernelGGL(proj_kernel, dim3(768), dim3(256), 0, stream,
                       xb, wb, (const float*)d_in[4], (const float*)d_in[6],
                       (const float*)d_in[8], qkv);

    hipLaunchKernelGGL(attn_kernel, dim3(512), dim3(512), 0, stream,
                       qkv, qkv + XE, qkv + 2L * XE, ob);

    hipLaunchKernelGGL(out_kernel, dim3(256), dim3(256), 0, stream,
                       ob, wb + 3L * WE, (const float*)d_in[10], (float*)d_out);
}

// Round 21
// 133.518 us; speedup vs baseline: 1.0325x; 1.0325x over previous
//
#include <hip/hip_runtime.h>

// ---------------------------------------------------------------------------
// MultiHeadAttention forward, MI355X (gfx950).
// fp32->bf16 convert; Q/K/V projections (bf16 MFMA GEMM, BK=32, XCD-chunked
// block mapping); flash attention v4b with XCD-chunked grid (each XCD owns
// 4 heads -> K/V L2-resident; 8 waves x 16q, swapped-QK^T, defer-max,
// cvt_pk P-pack, l via ones-MFMA, counted-vmcnt pipeline); out proj.
// ---------------------------------------------------------------------------

#define D_MODEL 1024
#define NHEADS  16
#define DKH     64
#define SEQ     2048
#define BATCH   2
#define MTOT    (BATCH * SEQ)            // 4096 rows
#define XE      ((long)MTOT * D_MODEL)   // 4194304 elems
#define WE      ((long)D_MODEL * D_MODEL)
#define QSCALE  0.18033688011112042f     // 0.125 * log2(e): softmax in exp2 domain

typedef __attribute__((ext_vector_type(8))) short short8v;   // 8 x bf16 (4 VGPR)
typedef __attribute__((ext_vector_type(4))) short short4v;   // 4 x bf16
typedef __attribute__((ext_vector_type(4))) float f32x4;     // MFMA C/D frag

typedef __attribute__((address_space(1))) void as1_void;
typedef __attribute__((address_space(3))) void as3_void;

__device__ __forceinline__ void gload16(const void* g, void* l) {
    __builtin_amdgcn_global_load_lds((const as1_void*)g, (as3_void*)l, 16, 0, 0);
}

__device__ __forceinline__ unsigned short f2bf(float x) {
    unsigned int u = __float_as_uint(x);
    u += 0x7FFFu + ((u >> 16) & 1u);     // RNE
    return (unsigned short)(u >> 16);
}

// native v_exp_f32: computes 2^x (avoid __exp2f: glibc name collision)
__device__ __forceinline__ float fexp2(float x) {
    return __builtin_amdgcn_exp2f(x);
}

// hardware packed f32x2 -> bf16x2 (one VALU op for two converts)
__device__ __forceinline__ unsigned int cvt_pk_bf16(float lo, float hi) {
    unsigned int r;
    asm("v_cvt_pk_bf16_f32 %0, %1, %2" : "=v"(r) : "v"(lo), "v"(hi));
    return r;
}

// XOR swizzle for [rows][64 bf16] LDS tiles (128B rows).
__device__ __forceinline__ int swz_u(int row, int col) {
    int byte = (col << 1) ^ ((row & 7) << 4);
    return (row << 6) + (byte >> 1);
}

// Vt swizzle: slot bits from (d&6)|((d>>3)&1): write pairs and reads stay 2-way.
__device__ __forceinline__ int swz_v(int d, int kv) {
    int slot = (d & 6) | ((d >> 3) & 1);
    int byte = (kv << 1) ^ (slot << 4);
    return (d << 6) + (byte >> 1);
}

// ---------------------------------------------------------------------------
// fp32 -> bf16 convert, 7 arrays in one launch (blockIdx.y selects array)
// ---------------------------------------------------------------------------
struct ConvArgs {
    const float*    src[7];
    unsigned short* dst[7];
    int             n4[7];
};

__global__ __launch_bounds__(256) void convert_kernel(ConvArgs a) {
    int z = blockIdx.y;
    const float4*   s = (const float4*)a.src[z];
    unsigned short* d = a.dst[z];
    int n = a.n4[z];
    for (int i = blockIdx.x * blockDim.x + threadIdx.x; i < n;
         i += gridDim.x * blockDim.x) {
        float4 v = s[i];
        ushort4 o;
        o.x = f2bf(v.x); o.y = f2bf(v.y); o.z = f2bf(v.z); o.w = f2bf(v.w);
        *(ushort4*)(d + 4L * i) = o;
    }
}

// ---------------------------------------------------------------------------
// GEMM: C[M,N] = A[M,K] * Bm[N,K]^T  (both K-major), + bias, * scale.
// 128x128 tile, BK=32, 4 waves (2x2), 16x16x32 bf16 MFMA, global_load_lds.
// m0/n0 passed in (callers apply XCD-chunked block mapping).
// ---------------------------------------------------------------------------
__device__ __forceinline__ void stv(float* p, float v)          { *p = v; }
__device__ __forceinline__ void stv(unsigned short* p, float v) { *p = f2bf(v); }

template <typename OutT>
__device__ __forceinline__ void gemm_core(const unsigned short* __restrict__ A,
                                          const unsigned short* __restrict__ Bm,
                                          const float* __restrict__ bias,
                                          OutT* __restrict__ C,
                                          int K, int N, float scale,
                                          long m0, long n0) {
    __shared__ unsigned short As[128 * 32];
    __shared__ unsigned short Bs[128 * 32];

    const int t    = threadIdx.x;
    const int lane = t & 63;
    const int w    = t >> 6;
    const int wm   = w >> 1, wn = w & 1;
    const int l15  = lane & 15, g = lane >> 4;

    f32x4 acc[4][4] = {};

    const int idx0 = t, idx1 = t + 256;
    const int r0 = idx0 >> 2, c0 = (idx0 & 3) * 8;
    const int r1 = idx1 >> 2, c1 = (idx1 & 3) * 8;
    const unsigned short* pa0 = A  + (m0 + r0) * K + c0;
    const unsigned short* pa1 = A  + (m0 + r1) * K + c1;
    const unsigned short* pb0 = Bm + (n0 + r0) * K + c0;
    const unsigned short* pb1 = Bm + (n0 + r1) * K + c1;

    for (int k0 = 0; k0 < K; k0 += 32) {
        gload16(pa0 + k0, &As[idx0 * 8]);
        gload16(pa1 + k0, &As[idx1 * 8]);
        gload16(pb0 + k0, &Bs[idx0 * 8]);
        gload16(pb1 + k0, &Bs[idx1 * 8]);
        __syncthreads();   // drains vmcnt -> LDS valid

        short8v af[4], bf_[4];
#pragma unroll
        for (int mf = 0; mf < 4; ++mf)
            af[mf] = *(const short8v*)&As[(wm * 64 + mf * 16 + l15) * 32 + g * 8];
#pragma unroll
        for (int nf = 0; nf < 4; ++nf)
            bf_[nf] = *(const short8v*)&Bs[(wn * 64 + nf * 16 + l15) * 32 + g * 8];
#pragma unroll
        for (int mf = 0; mf < 4; ++mf)
#pragma unroll
            for (int nf = 0; nf < 4; ++nf)
                acc[mf][nf] = __builtin_amdgcn_mfma_f32_16x16x32_bf16(
                    af[mf], bf_[nf], acc[mf][nf], 0, 0, 0);
        __syncthreads();   // reads done before restage
    }

    float bvv[4];
#pragma unroll
    for (int nf = 0; nf < 4; ++nf)
        bvv[nf] = bias[n0 + wn * 64 + nf * 16 + l15];

#pragma unroll
    for (int mf = 0; mf < 4; ++mf)
#pragma unroll
        for (int nf = 0; nf < 4; ++nf)
#pragma unroll
            for (int r = 0; r < 4; ++r) {
                // m89-verified C/D layout: col = lane&15, row = (lane>>4)*4+reg
                long row = m0 + wm * 64 + mf * 16 + g * 4 + r;
                long col = n0 + wn * 64 + nf * 16 + l15;
                float v = (acc[mf][nf][r] + bvv[nf]) * scale;
                stv(C + row * (long)N + col, v);
            }
}

// proj: 768 blocks, 1-D. XCD-chunked decode (T1, bijective: 768 % 8 == 0).
__global__ __launch_bounds__(256) void proj_kernel(
    const unsigned short* __restrict__ xb, const unsigned short* __restrict__ wb,
    const float* __restrict__ bq, const float* __restrict__ bk,
    const float* __restrict__ bv, unsigned short* __restrict__ qkv) {
    const int bid = blockIdx.x;
    const int xcd = bid & 7;
    const int k   = bid >> 3;            // 0..95 = 4(y) x 8(x) x 3(z)
    const int ty  = (xcd << 2) | (k & 3);
    const int tx  = (k >> 2) & 7;
    const int z   = k >> 5;
    const float* bias = (z == 0) ? bq : (z == 1) ? bk : bv;
    float scale = (z == 0) ? QSCALE : 1.0f;
    gemm_core<unsigned short>(xb + (long)z * XE, wb + (long)z * WE, bias,
                              qkv + (long)z * XE, D_MODEL, D_MODEL, scale,
                              (long)ty * 128, (long)tx * 128);
}

// out: 256 blocks, 1-D, same chunked decode (256 % 8 == 0).
__global__ __launch_bounds__(256) void out_kernel(
    const unsigned short* __restrict__ ob, const unsigned short* __restrict__ wo,
    const float* __restrict__ bo, float* __restrict__ out) {
    const int bid = blockIdx.x;
    const int xcd = bid & 7;
    const int k   = bid >> 3;            // 0..31 = 4(y) x 8(x)
    const int ty  = (xcd << 2) | (k & 3);
    const int tx  = k >> 2;
    gemm_core<float>(ob, wo, bo, out, D_MODEL, D_MODEL, 1.0f,
                     (long)ty * 128, (long)tx * 128);
}

// ---------------------------------------------------------------------------
// Flash attention v4b + XCD-chunked grid: 512 blocks 1-D; XCD i owns heads
// 4i..4i+3 (all 16 q-blocks) -> per-XCD K/V working set 2 MB, L2-resident
// (v8c measured FETCH 71.7 -> 12.3 MB with this decode). Block = 128 q rows,
// one (b,h); 8 waves x 16 rows. Swapped QK^T, defer-max THR=8, cvt_pk
// P-pack, l via ones-MFMA, double-buffered K/V counted-vmcnt pipeline.
// ---------------------------------------------------------------------------
#define KVB 4096   // elems per K/V buffer (64 rows x 64)

__global__ __launch_bounds__(512) void attn_kernel(
    const unsigned short* __restrict__ Qb, const unsigned short* __restrict__ Kb,
    const unsigned short* __restrict__ Vb, unsigned short* __restrict__ Ob) {
    __shared__ alignas(16) unsigned short Ks[2 * KVB];     // 16 KB
    __shared__ alignas(16) unsigned short Vt[2 * KVB];     // 16 KB  V^T [d][kv]
    __shared__ alignas(16) unsigned short Ps[8][16 * 64];  // 16 KB  per-wave P
    __shared__ alignas(16) float corrS[8][16];

    const int t = threadIdx.x, lane = t & 63, w = t >> 6;
    const int l15 = lane & 15, g = lane >> 4;
    // XCD-chunked decode: 512 blocks; xcd owns heads 4*xcd..4*xcd+3
    const int bid = blockIdx.x;
    const int xcd = bid & 7;
    const int kk2 = bid >> 3;              // 0..63
    const int bh  = (xcd << 2) | (kk2 & 3);
    const int qb  = kk2 >> 2;              // 0..15
    const long headoff = (long)(bh >> 4) * SEQ * D_MODEL + (long)(bh & 15) * DKH;
    const int q0w = qb * 128 + w * 16;

    // Q rows -> B-frag registers (scale 0.125*log2e folded at projection)
    short8v qf[2];
#pragma unroll
    for (int ks = 0; ks < 2; ++ks)
        qf[ks] = *(const short8v*)(Qb + headoff +
            (long)(q0w + l15) * D_MODEL + ks * 32 + g * 8);

    // B-frag of all-ones (bf16 1.0 = 0x3F80) for the l-sum MFMA
    short8v onesv;
#pragma unroll
    for (int j = 0; j < 8; ++j) onesv[j] = (short)0x3F80;

    f32x4 o[4] = {};
    f32x4 ol = {};               // l accumulator via mfma(pf, ones, ol)
    float mrun = -3.0e38f;

    const int vd0  = (t & 31) * 2;    // V gather: this thread's d pair
    const int vkv0 = (t >> 5) * 4;    // and 4-kv group (t>>5 in 0..15)
    const int kr0 = t >> 3, ks0 = t & 7;   // K stage: one gload16 per thread

    unsigned int va[4];   // in-flight V gather regs (issue-early)

#define ISSUE_V(kt)                                                        \
    _Pragma("unroll")                                                      \
    for (int j = 0; j < 4; ++j)                                            \
        va[j] = *(const unsigned int*)(Vb + headoff +                      \
            (long)((kt) + vkv0 + j) * D_MODEL + vd0);

#define ISSUE_K(kt, off)                                                   \
    gload16(Kb + headoff + (long)((kt) + kr0) * D_MODEL +                  \
                ((ks0 ^ (kr0 & 7)) << 3), &Ks[(off) + t * 8]);

#define WRITE_V(off)                                                       \
    {                                                                      \
        short4v ra, rb;                                                    \
        _Pragma("unroll")                                                  \
        for (int j = 0; j < 4; ++j) {                                      \
            ra[j] = (short)(va[j] & 0xffffu);                              \
            rb[j] = (short)(va[j] >> 16);                                  \
        }                                                                  \
        *(short4v*)&Vt[(off) + swz_v(vd0,     vkv0)] = ra;                 \
        *(short4v*)&Vt[(off) + swz_v(vd0 + 1, vkv0)] = rb;                 \
    }

    // ---- prologue: drain Q loads, stage tile 0 into buffer 0 ----
    asm volatile("s_waitcnt vmcnt(0)" ::: "memory");
    ISSUE_V(0);
    ISSUE_K(0, 0);
    WRITE_V(0);              // compiler waits va (vmcnt(1)); K stays in flight
    int cur = 0;

    for (int it = 0; it < SEQ / 64; ++it) {
        const int nxt = cur ^ 1;
        const int ktn = (((it + 1) & (SEQ / 64 - 1))) * 64;  // wrapped prefetch
        ISSUE_V(ktn);
        ISSUE_K(ktn, nxt * KVB);
        // outstanding now: K(cur)=1 + V(nxt)=4 + K(nxt)=1 = 6; complete oldest
        asm volatile("s_waitcnt vmcnt(5)" ::: "memory");
        asm volatile("s_waitcnt lgkmcnt(0)" ::: "memory");
        __builtin_amdgcn_sched_barrier(0);
        __builtin_amdgcn_s_barrier();
        __builtin_amdgcn_sched_barrier(0);

        const int kO = cur * KVB;

        // ---- S^T = K * Q^T : lane holds S^T[kv = mf*16+g*4+r][q = l15] ----
        f32x4 st[4] = {};
        __builtin_amdgcn_s_setprio(1);
#pragma unroll
        for (int ks = 0; ks < 2; ++ks)
#pragma unroll
            for (int mf = 0; mf < 4; ++mf) {
                short8v kf = *(const short8v*)&Ks[kO + swz_u(mf * 16 + l15, ks * 32 + g * 8)];
                st[mf] = __builtin_amdgcn_mfma_f32_16x16x32_bf16(
                    kf, qf[ks], st[mf], 0, 0, 0);
            }
        __builtin_amdgcn_s_setprio(0);

        // ---- online softmax (exp2 domain), defer-max THR=8 ----
        float vmax = st[0][0];
#pragma unroll
        for (int mf = 0; mf < 4; ++mf)
#pragma unroll
            for (int r = 0; r < 4; ++r)
                vmax = fmaxf(vmax, st[mf][r]);
        vmax = fmaxf(vmax, __shfl_xor(vmax, 16));
        vmax = fmaxf(vmax, __shfl_xor(vmax, 32));

        const bool grow = __any(vmax > mrun + 8.0f);
        if (grow) {
            float mnew = fmaxf(mrun, vmax);
            float corr = fexp2(mrun - mnew);
            mrun = mnew;
            if (g == 0) corrS[w][l15] = corr;
        }

#pragma unroll
        for (int mf = 0; mf < 4; ++mf)
#pragma unroll
            for (int r = 0; r < 4; ++r)
                st[mf][r] = fexp2(st[mf][r] - mrun);

        // P: packed bf16 pairs (cvt_pk) -> b64 swizzled writes (wave-private)
        unsigned short* Pw = Ps[w];
#pragma unroll
        for (int mf = 0; mf < 4; ++mf) {
            uint2 pk;
            pk.x = cvt_pk_bf16(st[mf][0], st[mf][1]);
            pk.y = cvt_pk_bf16(st[mf][2], st[mf][3]);
            *(uint2*)&Pw[swz_u(l15, mf * 16 + g * 4)] = pk;
        }

        // rescale O and ol only when max grew (corr keyed by q = g*4 + r)
        if (grow) {
            float4 cv = *(const float4*)&corrS[w][g * 4];
#pragma unroll
            for (int nd = 0; nd < 4; ++nd)
#pragma unroll
                for (int r = 0; r < 4; ++r)
                    o[nd][r] *= cv[r];
#pragma unroll
            for (int r = 0; r < 4; ++r) ol[r] *= cv[r];
        }

        // ---- O += P * V ; ol += P * ones (row-sum of P) ----
        __builtin_amdgcn_s_setprio(1);
#pragma unroll
        for (int ks2 = 0; ks2 < 2; ++ks2) {
            short8v pf = *(const short8v*)&Pw[swz_u(l15, ks2 * 32 + g * 8)];
            ol = __builtin_amdgcn_mfma_f32_16x16x32_bf16(
                pf, onesv, ol, 0, 0, 0);
#pragma unroll
            for (int nd = 0; nd < 4; ++nd) {
                short8v vf = *(const short8v*)&Vt[kO + swz_v(nd * 16 + l15, ks2 * 32 + g * 8)];
                o[nd] = __builtin_amdgcn_mfma_f32_16x16x32_bf16(
                    pf, vf, o[nd], 0, 0, 0);
            }
        }
        __builtin_amdgcn_s_setprio(0);

        // ---- write next tile's V (regs arrived; compiler waits vmcnt) ----
        WRITE_V(nxt * KVB);
        cur = nxt;
    }

    // ---- epilogue: O /= l (l = ol, same D-layout as o) ----
#pragma unroll
    for (int r = 0; r < 4; ++r) {
        float inv = 1.f / (ol[r] + 1e-9f);
        long rowoff = headoff + (long)(q0w + g * 4 + r) * D_MODEL;
#pragma unroll
        for (int nd = 0; nd < 4; ++nd)
            Ob[rowoff + nd * 16 + l15] = f2bf(o[nd][r] * inv);
    }
#undef ISSUE_V
#undef ISSUE_K
#undef WRITE_V
}

// ---------------------------------------------------------------------------
// Launch
// ---------------------------------------------------------------------------
extern "C" void kernel_launch(void* const* d_in, const int* in_sizes, int n_in,
                              void* d_out, int out_size, void* d_ws, size_t ws_size,
                              hipStream_t stream) {
    // d_in order: 0 q, 1 k, 2 v, 3 Wq, 4 bq, 5 Wk, 6 bk, 7 Wv, 8 bv, 9 Wo, 10 bo
    unsigned short* ws  = (unsigned short*)d_ws;
    unsigned short* xb  = ws;                       // 3*XE  bf16 inputs q,k,v
    unsigned short* wb  = ws + 3L * XE;             // 4*WE  bf16 weights
    unsigned short* qkv = ws + 3L * XE + 4L * WE;   // 3*XE  Q(scaled), K, V
    unsigned short* ob  = qkv + 3L * XE;            // XE    attention output

    ConvArgs ca;
    ca.src[0] = (const float*)d_in[0]; ca.dst[0] = xb;           ca.n4[0] = (int)(XE / 4);
    ca.src[1] = (const float*)d_in[1]; ca.dst[1] = xb + XE;      ca.n4[1] = (int)(XE / 4);
    ca.src[2] = (const float*)d_in[2]; ca.dst[2] = xb + 2L * XE; ca.n4[2] = (int)(XE / 4);
    ca.src[3] = (const float*)d_in[3]; ca.dst[3] = wb;           ca.n4[3] = (int)(WE / 4);
    ca.src[4] = (const float*)d_in[5]; ca.dst[4] = wb + WE;      ca.n4[4] = (int)(WE / 4);
    ca.src[5] = (const float*)d_in[7]; ca.dst[5] = wb + 2L * WE; ca.n4[5] = (int)(WE / 4);
    ca.src[6] = (const float*)d_in[9]; ca.dst[6] = wb + 3L * WE; ca.n4[6] = (int)(WE / 4);

    hipLaunchKernelGGL(convert_kernel, dim3(512, 7), dim3(256), 0, stream, ca);

    hipLaunchKernelGGL(proj_kernel, dim3(768), dim3(256), 0, stream,
                       xb, wb, (const float*)d_in[4], (const float*)d_in[6],
                       (const float*)d_in[8], qkv);

    hipLaunchKernelGGL(attn_kernel, dim3(512), dim3(512), 0, stream,
                       qkv, qkv + XE, qkv + 2L * XE, ob);

    hipLaunchKernelGGL(out_kernel, dim3(256), dim3(256), 0, stream,
                       ob, wb + 3L * WE, (const float*)d_in[10], (float*)d_out);
}

// Round 23
// 132.697 us; speedup vs baseline: 1.0389x; 1.0062x over previous
//
#include <hip/hip_runtime.h>

// ---------------------------------------------------------------------------
// MultiHeadAttention forward, MI355X (gfx950).
// fp32->bf16 convert; Q/K/V projections (256x256/BK=64 bf16 MFMA GEMM,
// 8 waves, XOR-swizzled staging, counted-vmcnt dbuf pipeline with
// post-compute barrier (WAR-race fix), XCD-chunked); flash attention v4b +
// XCD-chunked grid; output projection (128^2 core).
// ---------------------------------------------------------------------------

#define D_MODEL 1024
#define NHEADS  16
#define DKH     64
#define SEQ     2048
#define BATCH   2
#define MTOT    (BATCH * SEQ)            // 4096 rows
#define XE      ((long)MTOT * D_MODEL)   // 4194304 elems
#define WE      ((long)D_MODEL * D_MODEL)
#define QSCALE  0.18033688011112042f     // 0.125 * log2(e): softmax in exp2 domain

typedef __attribute__((ext_vector_type(8))) short short8v;   // 8 x bf16 (4 VGPR)
typedef __attribute__((ext_vector_type(4))) short short4v;   // 4 x bf16
typedef __attribute__((ext_vector_type(4))) float f32x4;     // MFMA C/D frag

typedef __attribute__((address_space(1))) void as1_void;
typedef __attribute__((address_space(3))) void as3_void;

__device__ __forceinline__ void gload16(const void* g, void* l) {
    __builtin_amdgcn_global_load_lds((const as1_void*)g, (as3_void*)l, 16, 0, 0);
}

__device__ __forceinline__ unsigned short f2bf(float x) {
    unsigned int u = __float_as_uint(x);
    u += 0x7FFFu + ((u >> 16) & 1u);     // RNE
    return (unsigned short)(u >> 16);
}

// native v_exp_f32: computes 2^x (avoid __exp2f: glibc name collision)
__device__ __forceinline__ float fexp2(float x) {
    return __builtin_amdgcn_exp2f(x);
}

// hardware packed f32x2 -> bf16x2 (one VALU op for two converts)
__device__ __forceinline__ unsigned int cvt_pk_bf16(float lo, float hi) {
    unsigned int r;
    asm("v_cvt_pk_bf16_f32 %0, %1, %2" : "=v"(r) : "v"(lo), "v"(hi));
    return r;
}

// XOR swizzle for [rows][64 bf16] LDS tiles (128B rows).
__device__ __forceinline__ int swz_u(int row, int col) {
    int byte = (col << 1) ^ ((row & 7) << 4);
    return (row << 6) + (byte >> 1);
}

// Vt swizzle: slot bits from (d&6)|((d>>3)&1): write pairs and reads stay 2-way.
__device__ __forceinline__ int swz_v(int d, int kv) {
    int slot = (d & 6) | ((d >> 3) & 1);
    int byte = (kv << 1) ^ (slot << 4);
    return (d << 6) + (byte >> 1);
}

// ---------------------------------------------------------------------------
// fp32 -> bf16 convert, 7 arrays in one launch (blockIdx.y selects array)
// ---------------------------------------------------------------------------
struct ConvArgs {
    const float*    src[7];
    unsigned short* dst[7];
    int             n4[7];
};

__global__ __launch_bounds__(256) void convert_kernel(ConvArgs a) {
    int z = blockIdx.y;
    const float4*   s = (const float4*)a.src[z];
    unsigned short* d = a.dst[z];
    int n = a.n4[z];
    for (int i = blockIdx.x * blockDim.x + threadIdx.x; i < n;
         i += gridDim.x * blockDim.x) {
        float4 v = s[i];
        ushort4 o;
        o.x = f2bf(v.x); o.y = f2bf(v.y); o.z = f2bf(v.z); o.w = f2bf(v.w);
        *(ushort4*)(d + 4L * i) = o;
    }
}

// ---------------------------------------------------------------------------
// proj GEMM v2b: 256x256 tile, BK=64, 8 waves (2M x 4N), 512 threads.
// Staging: XOR-swizzled source + linear gload_lds dest (round-15 proven).
// Pipeline: dbuf + counted vmcnt(8) + barrier BEFORE compute, and a second
// barrier AFTER compute (v2's single-barrier had a WAR race: next iter's
// PSTAGE overwrote the buffer slower waves were still reading at the tail
// of their MFMA phase -> absmax 2e-2).
// Grid 192 = 2(M/xcd) x 4(N) x 3(z) x 8 xcd, XCD-chunked.
// ---------------------------------------------------------------------------
#define PBM 256
#define PBK 64
#define PTILE (PBM * PBK)     // 16384 elems = 32 KB per matrix per buffer

__global__ __launch_bounds__(512) void proj_kernel(
    const unsigned short* __restrict__ xb, const unsigned short* __restrict__ wb,
    const float* __restrict__ bq, const float* __restrict__ bk,
    const float* __restrict__ bv, unsigned short* __restrict__ qkv) {
    __shared__ unsigned short As[2 * PTILE];   // 64 KB
    __shared__ unsigned short Bs[2 * PTILE];   // 64 KB

    const int t    = threadIdx.x;
    const int lane = t & 63;
    const int w    = t >> 6;
    const int wm   = w >> 2, wn = w & 3;        // 2 x 4 wave grid
    const int l15  = lane & 15, g = lane >> 4;

    // XCD-chunked decode: 192 blocks; xcd owns M-tiles 2*xcd..2*xcd+1
    const int bid = blockIdx.x;
    const int xcd = bid & 7;
    const int k   = bid >> 3;                   // 0..23 = 2(M) x 4(N) x 3(z)
    const int ty  = (xcd << 1) | (k & 1);       // M-tile 0..15
    const int tx  = (k >> 1) & 3;               // N-tile 0..3
    const int z   = k >> 3;
    const float* bias = (z == 0) ? bq : (z == 1) ? bk : bv;
    const float scale = (z == 0) ? QSCALE : 1.0f;

    const unsigned short* A  = xb + (long)z * XE;
    const unsigned short* Bm = wb + (long)z * WE;
    unsigned short*       C  = qkv + (long)z * XE;
    const long m0 = (long)ty * PBM;
    const long n0 = (long)tx * PBM;
    const int  K  = D_MODEL;

    f32x4 acc[8][4] = {};

    // staging geometry: 2048 chunks per matrix, 4 per thread per matrix
    int srow[4], scol[4];
#pragma unroll
    for (int c = 0; c < 4; ++c) {
        int idx = t + c * 512;
        srow[c] = idx >> 3;
        scol[c] = ((idx & 7) ^ (srow[c] & 7)) * 8;
    }

#define PSTAGE(k0, buf)                                                    \
    _Pragma("unroll")                                                      \
    for (int c = 0; c < 4; ++c) {                                          \
        int idx = t + c * 512;                                             \
        gload16(A  + (m0 + srow[c]) * K + (k0) + scol[c],                  \
                &As[(buf) * PTILE + idx * 8]);                             \
        gload16(Bm + (n0 + srow[c]) * K + (k0) + scol[c],                  \
                &Bs[(buf) * PTILE + idx * 8]);                             \
    }

    // ---- prologue: stage tile 0 into buffer 0 ----
    PSTAGE(0, 0);
    int cur = 0;

    for (int it = 0; it < K / PBK; ++it) {          // 16 iters
        const int nxt = cur ^ 1;
        const int kn  = ((it + 1) * PBK) & (K - 1); // wrapped prefetch
        PSTAGE(kn, nxt);
        // outstanding: cur 8 + nxt 8 = 16; complete the oldest 8 (cur tile)
        asm volatile("s_waitcnt vmcnt(8)" ::: "memory");
        asm volatile("s_waitcnt lgkmcnt(0)" ::: "memory");
        __builtin_amdgcn_sched_barrier(0);
        __builtin_amdgcn_s_barrier();
        __builtin_amdgcn_sched_barrier(0);

        const unsigned short* Ab = &As[cur * PTILE];
        const unsigned short* Bb = &Bs[cur * PTILE];

#pragma unroll
        for (int kk = 0; kk < 2; ++kk) {
            short8v bf_[4];
#pragma unroll
            for (int nf = 0; nf < 4; ++nf) {
                int r = wn * 64 + nf * 16 + l15;
                bf_[nf] = *(const short8v*)&Bb[r * 64 + (((kk * 4 + g) ^ (r & 7)) * 8)];
            }
#pragma unroll
            for (int mh = 0; mh < 2; ++mh) {
                short8v af_[4];
#pragma unroll
                for (int i = 0; i < 4; ++i) {
                    int r = wm * 128 + (mh * 4 + i) * 16 + l15;
                    af_[i] = *(const short8v*)&Ab[r * 64 + (((kk * 4 + g) ^ (r & 7)) * 8)];
                }
                __builtin_amdgcn_s_setprio(1);
#pragma unroll
                for (int i = 0; i < 4; ++i)
#pragma unroll
                    for (int nf = 0; nf < 4; ++nf)
                        acc[mh * 4 + i][nf] = __builtin_amdgcn_mfma_f32_16x16x32_bf16(
                            af_[i], bf_[nf], acc[mh * 4 + i][nf], 0, 0, 0);
                __builtin_amdgcn_s_setprio(0);
            }
        }

        // ---- barrier2: all waves done READING buf cur before next PSTAGE
        //      overwrites it (fixes v2's WAR race) ----
        asm volatile("s_waitcnt lgkmcnt(0)" ::: "memory");
        __builtin_amdgcn_sched_barrier(0);
        __builtin_amdgcn_s_barrier();
        __builtin_amdgcn_sched_barrier(0);
        cur = nxt;
    }

    // ---- epilogue: bias + scale, bf16 write ----
    float bvv[4];
#pragma unroll
    for (int nf = 0; nf < 4; ++nf)
        bvv[nf] = bias[n0 + wn * 64 + nf * 16 + l15];

#pragma unroll
    for (int mf = 0; mf < 8; ++mf)
#pragma unroll
        for (int nf = 0; nf < 4; ++nf)
#pragma unroll
            for (int r = 0; r < 4; ++r) {
                long row = m0 + wm * 128 + mf * 16 + g * 4 + r;
                long col = n0 + wn * 64 + nf * 16 + l15;
                C[row * (long)D_MODEL + col] =
                    f2bf((acc[mf][nf][r] + bvv[nf]) * scale);
            }
#undef PSTAGE
}

// ---------------------------------------------------------------------------
// out GEMM: proven 128x128/BK=32 core (round-17), XCD-chunked, 256 blocks.
// ---------------------------------------------------------------------------
__global__ __launch_bounds__(256) void out_kernel(
    const unsigned short* __restrict__ ob, const unsigned short* __restrict__ wo,
    const float* __restrict__ bo, float* __restrict__ out) {
    __shared__ unsigned short As[128 * 32];
    __shared__ unsigned short Bs[128 * 32];

    const int t    = threadIdx.x;
    const int lane = t & 63;
    const int w    = t >> 6;
    const int wm   = w >> 1, wn = w & 1;
    const int l15  = lane & 15, g = lane >> 4;

    const int bid = blockIdx.x;
    const int xcd = bid & 7;
    const int k   = bid >> 3;            // 0..31 = 4(y) x 8(x)
    const long m0 = (long)((xcd << 2) | (k & 3)) * 128;
    const long n0 = (long)(k >> 2) * 128;
    const int  K  = D_MODEL, N = D_MODEL;

    f32x4 acc[4][4] = {};

    const int idx0 = t, idx1 = t + 256;
    const int r0 = idx0 >> 2, c0 = (idx0 & 3) * 8;
    const int r1 = idx1 >> 2, c1 = (idx1 & 3) * 8;
    const unsigned short* pa0 = ob + (m0 + r0) * K + c0;
    const unsigned short* pa1 = ob + (m0 + r1) * K + c1;
    const unsigned short* pb0 = wo + (n0 + r0) * K + c0;
    const unsigned short* pb1 = wo + (n0 + r1) * K + c1;

    for (int k0 = 0; k0 < K; k0 += 32) {
        gload16(pa0 + k0, &As[idx0 * 8]);
        gload16(pa1 + k0, &As[idx1 * 8]);
        gload16(pb0 + k0, &Bs[idx0 * 8]);
        gload16(pb1 + k0, &Bs[idx1 * 8]);
        __syncthreads();

        short8v af[4], bf_[4];
#pragma unroll
        for (int mf = 0; mf < 4; ++mf)
            af[mf] = *(const short8v*)&As[(wm * 64 + mf * 16 + l15) * 32 + g * 8];
#pragma unroll
        for (int nf = 0; nf < 4; ++nf)
            bf_[nf] = *(const short8v*)&Bs[(wn * 64 + nf * 16 + l15) * 32 + g * 8];
#pragma unroll
        for (int mf = 0; mf < 4; ++mf)
#pragma unroll
            for (int nf = 0; nf < 4; ++nf)
                acc[mf][nf] = __builtin_amdgcn_mfma_f32_16x16x32_bf16(
                    af[mf], bf_[nf], acc[mf][nf], 0, 0, 0);
        __syncthreads();
    }

    float bvv[4];
#pragma unroll
    for (int nf = 0; nf < 4; ++nf)
        bvv[nf] = bo[n0 + wn * 64 + nf * 16 + l15];

#pragma unroll
    for (int mf = 0; mf < 4; ++mf)
#pragma unroll
        for (int nf = 0; nf < 4; ++nf)
#pragma unroll
            for (int r = 0; r < 4; ++r) {
                long row = m0 + wm * 64 + mf * 16 + g * 4 + r;
                long col = n0 + wn * 64 + nf * 16 + l15;
                out[row * (long)N + col] = acc[mf][nf][r] + bvv[nf];
            }
}

// ---------------------------------------------------------------------------
// Flash attention v4b + XCD-chunked grid (round-21, measured 63.0 us).
// ---------------------------------------------------------------------------
#define KVB 4096   // elems per K/V buffer (64 rows x 64)

__global__ __launch_bounds__(512) void attn_kernel(
    const unsigned short* __restrict__ Qb, const unsigned short* __restrict__ Kb,
    const unsigned short* __restrict__ Vb, unsigned short* __restrict__ Ob) {
    __shared__ alignas(16) unsigned short Ks[2 * KVB];     // 16 KB
    __shared__ alignas(16) unsigned short Vt[2 * KVB];     // 16 KB  V^T [d][kv]
    __shared__ alignas(16) unsigned short Ps[8][16 * 64];  // 16 KB  per-wave P
    __shared__ alignas(16) float corrS[8][16];

    const int t = threadIdx.x, lane = t & 63, w = t >> 6;
    const int l15 = lane & 15, g = lane >> 4;
    const int bid = blockIdx.x;
    const int xcd = bid & 7;
    const int kk2 = bid >> 3;              // 0..63
    const int bh  = (xcd << 2) | (kk2 & 3);
    const int qb  = kk2 >> 2;              // 0..15
    const long headoff = (long)(bh >> 4) * SEQ * D_MODEL + (long)(bh & 15) * DKH;
    const int q0w = qb * 128 + w * 16;

    short8v qf[2];
#pragma unroll
    for (int ks = 0; ks < 2; ++ks)
        qf[ks] = *(const short8v*)(Qb + headoff +
            (long)(q0w + l15) * D_MODEL + ks * 32 + g * 8);

    short8v onesv;
#pragma unroll
    for (int j = 0; j < 8; ++j) onesv[j] = (short)0x3F80;

    f32x4 o[4] = {};
    f32x4 ol = {};
    float mrun = -3.0e38f;

    const int vd0  = (t & 31) * 2;
    const int vkv0 = (t >> 5) * 4;
    const int kr0 = t >> 3, ks0 = t & 7;

    unsigned int va[4];

#define ISSUE_V(kt)                                                        \
    _Pragma("unroll")                                                      \
    for (int j = 0; j < 4; ++j)                                            \
        va[j] = *(const unsigned int*)(Vb + headoff +                      \
            (long)((kt) + vkv0 + j) * D_MODEL + vd0);

#define ISSUE_K(kt, off)                                                   \
    gload16(Kb + headoff + (long)((kt) + kr0) * D_MODEL +                  \
                ((ks0 ^ (kr0 & 7)) << 3), &Ks[(off) + t * 8]);

#define WRITE_V(off)                                                       \
    {                                                                      \
        short4v ra, rb;                                                    \
        _Pragma("unroll")                                                  \
        for (int j = 0; j < 4; ++j) {                                      \
            ra[j] = (short)(va[j] & 0xffffu);                              \
            rb[j] = (short)(va[j] >> 16);                                  \
        }                                                                  \
        *(short4v*)&Vt[(off) + swz_v(vd0,     vkv0)] = ra;                 \
        *(short4v*)&Vt[(off) + swz_v(vd0 + 1, vkv0)] = rb;                 \
    }

    asm volatile("s_waitcnt vmcnt(0)" ::: "memory");
    ISSUE_V(0);
    ISSUE_K(0, 0);
    WRITE_V(0);
    int cur = 0;

    for (int it = 0; it < SEQ / 64; ++it) {
        const int nxt = cur ^ 1;
        const int ktn = (((it + 1) & (SEQ / 64 - 1))) * 64;
        ISSUE_V(ktn);
        ISSUE_K(ktn, nxt * KVB);
        asm volatile("s_waitcnt vmcnt(5)" ::: "memory");
        asm volatile("s_waitcnt lgkmcnt(0)" ::: "memory");
        __builtin_amdgcn_sched_barrier(0);
        __builtin_amdgcn_s_barrier();
        __builtin_amdgcn_sched_barrier(0);

        const int kO = cur * KVB;

        f32x4 st[4] = {};
        __builtin_amdgcn_s_setprio(1);
#pragma unroll
        for (int ks = 0; ks < 2; ++ks)
#pragma unroll
            for (int mf = 0; mf < 4; ++mf) {
                short8v kf = *(const short8v*)&Ks[kO + swz_u(mf * 16 + l15, ks * 32 + g * 8)];
                st[mf] = __builtin_amdgcn_mfma_f32_16x16x32_bf16(
                    kf, qf[ks], st[mf], 0, 0, 0);
            }
        __builtin_amdgcn_s_setprio(0);

        float vmax = st[0][0];
#pragma unroll
        for (int mf = 0; mf < 4; ++mf)
#pragma unroll
            for (int r = 0; r < 4; ++r)
                vmax = fmaxf(vmax, st[mf][r]);
        vmax = fmaxf(vmax, __shfl_xor(vmax, 16));
        vmax = fmaxf(vmax, __shfl_xor(vmax, 32));

        const bool grow = __any(vmax > mrun + 8.0f);
        if (grow) {
            float mnew = fmaxf(mrun, vmax);
            float corr = fexp2(mrun - mnew);
            mrun = mnew;
            if (g == 0) corrS[w][l15] = corr;
        }

#pragma unroll
        for (int mf = 0; mf < 4; ++mf)
#pragma unroll
            for (int r = 0; r < 4; ++r)
                st[mf][r] = fexp2(st[mf][r] - mrun);

        unsigned short* Pw = Ps[w];
#pragma unroll
        for (int mf = 0; mf < 4; ++mf) {
            uint2 pk;
            pk.x = cvt_pk_bf16(st[mf][0], st[mf][1]);
            pk.y = cvt_pk_bf16(st[mf][2], st[mf][3]);
            *(uint2*)&Pw[swz_u(l15, mf * 16 + g * 4)] = pk;
        }

        if (grow) {
            float4 cv = *(const float4*)&corrS[w][g * 4];
#pragma unroll
            for (int nd = 0; nd < 4; ++nd)
#pragma unroll
                for (int r = 0; r < 4; ++r)
                    o[nd][r] *= cv[r];
#pragma unroll
            for (int r = 0; r < 4; ++r) ol[r] *= cv[r];
        }

        __builtin_amdgcn_s_setprio(1);
#pragma unroll
        for (int ks2 = 0; ks2 < 2; ++ks2) {
            short8v pf = *(const short8v*)&Pw[swz_u(l15, ks2 * 32 + g * 8)];
            ol = __builtin_amdgcn_mfma_f32_16x16x32_bf16(
                pf, onesv, ol, 0, 0, 0);
#pragma unroll
            for (int nd = 0; nd < 4; ++nd) {
                short8v vf = *(const short8v*)&Vt[kO + swz_v(nd * 16 + l15, ks2 * 32 + g * 8)];
                o[nd] = __builtin_amdgcn_mfma_f32_16x16x32_bf16(
                    pf, vf, o[nd], 0, 0, 0);
            }
        }
        __builtin_amdgcn_s_setprio(0);

        WRITE_V(nxt * KVB);
        cur = nxt;
    }

#pragma unroll
    for (int r = 0; r < 4; ++r) {
        float inv = 1.f / (ol[r] + 1e-9f);
        long rowoff = headoff + (long)(q0w + g * 4 + r) * D_MODEL;
#pragma unroll
        for (int nd = 0; nd < 4; ++nd)
            Ob[rowoff + nd * 16 + l15] = f2bf(o[nd][r] * inv);
    }
#undef ISSUE_V
#undef ISSUE_K
#undef WRITE_V
}

// ---------------------------------------------------------------------------
// Launch
// ---------------------------------------------------------------------------
extern "C" void kernel_launch(void* const* d_in, const int* in_sizes, int n_in,
                              void* d_out, int out_size, void* d_ws, size_t ws_size,
                              hipStream_t stream) {
    // d_in order: 0 q, 1 k, 2 v, 3 Wq, 4 bq, 5 Wk, 6 bk, 7 Wv, 8 bv, 9 Wo, 10 bo
    unsigned short* ws  = (unsigned short*)d_ws;
    unsigned short* xb  = ws;                       // 3*XE  bf16 inputs q,k,v
    unsigned short* wb  = ws + 3L * XE;             // 4*WE  bf16 weights
    unsigned short* qkv = ws + 3L * XE + 4L * WE;   // 3*XE  Q(scaled), K, V
    unsigned short* ob  = qkv + 3L * XE;            // XE    attention output

    ConvArgs ca;
    ca.src[0] = (const float*)d_in[0]; ca.dst[0] = xb;           ca.n4[0] = (int)(XE / 4);
    ca.src[1] = (const float*)d_in[1]; ca.dst[1] = xb + XE;      ca.n4[1] = (int)(XE / 4);
    ca.src[2] = (const float*)d_in[2]; ca.dst[2] = xb + 2L * XE; ca.n4[2] = (int)(XE / 4);
    ca.src[3] = (const float*)d_in[3]; ca.dst[3] = wb;           ca.n4[3] = (int)(WE / 4);
    ca.src[4] = (const float*)d_in[5]; ca.dst[4] = wb + WE;      ca.n4[4] = (int)(WE / 4);
    ca.src[5] = (const float*)d_in[7]; ca.dst[5] = wb + 2L * WE; ca.n4[5] = (int)(WE / 4);
    ca.src[6] = (const float*)d_in[9]; ca.dst[6] = wb + 3L * WE; ca.n4[6] = (int)(WE / 4);

    hipLaunchKernelGGL(convert_kernel, dim3(512, 7), dim3(256), 0, stream, ca);

    hipLaunchKernelGGL(proj_kernel, dim3(192), dim3(512), 0, stream,
                       xb, wb, (const float*)d_in[4], (const float*)d_in[6],
                       (const float*)d_in[8], qkv);

    hipLaunchKernelGGL(attn_kernel, dim3(512), dim3(512), 0, stream,
                       qkv, qkv + XE, qkv + 2L * XE, ob);

    hipLaunchKernelGGL(out_kernel, dim3(256), dim3(256), 0, stream,
                       ob, wb + 3L * WE, (const float*)d_in[10], (float*)d_out);
}